// Round 2
// baseline (236.767 us; speedup 1.0000x reference)
//
#include <hip/hip_runtime.h>
#include <math.h>

// Causal depthwise conv1d K=4 + SiLU. x (B=4, T=4096, C=2048) fp32, kernel (4, C) fp32.
// y[b,t,c] = silu( sum_j k[j,c] * x[b,t-j,c] ), zero-padded; next_cache = x[:, T-3:, :].
//
// R3 post-mortem: VGPR=36 proves the machine scheduler serialized every load into
//   load;waitcnt(0);use (no batch ever live). VALUBusy 9%, dur pinned at 82us across
//   two different source schedules -> latency-bound by compiler-forced serialization.
// R4: force-issue ALL 23 loads (3 halo + 16 rows + 4 kern) per thread BEFORE any
//   compute, fenced with sched_barrier(0) so the scheduler cannot sink loads into
//   the compute cluster. Consumption order == issue order -> graduated vmcnt(N)
//   pipelining. ~19KB in flight per wave >> Little's law for 6.3 TB/s.
//   Also: drop nontemporal stores (suspected 1.6 TB/s NT-path ceiling backpressuring
//   the shared VMEM queue); plain stores drain through L2.

#define B_   4
#define T_   4096
#define C_   2048
#define K_   4
#define C4_  (C_ / 4)   // 512 float4 groups per row
#define TT_  16         // timesteps per block

__device__ __forceinline__ float silu_f(float v) {
    // v * 1/(1+e^-v); raw v_rcp_f32 (approx, ~1ulp).
    return v * __builtin_amdgcn_rcpf(1.f + __expf(-v));
}

__global__ __launch_bounds__(C4_, 4) void dwconv_silu_kernel(
    const float4* __restrict__ x,      // [B, T, C4]
    const float4* __restrict__ kern,   // [K, C4]
    float4* __restrict__ y,            // [B, T, C4]
    float4* __restrict__ cache)        // [B, K-1, C4]
{
    const int c4 = threadIdx.x;        // 0..511
    const int b  = blockIdx.y;
    const int t0 = blockIdx.x * TT_;

    const float4* xr = x + ((size_t)b * T_ + t0) * C4_ + c4;
    float4*       yr = y + ((size_t)b * T_ + t0) * C4_ + c4;

    // a[0..2] = halo x[t0-3..t0-1]; a[3+i] = x[t0+i]. All indices compile-time
    // after unroll -> stays in VGPRs (76 regs of load destinations, forced live).
    float4 a[TT_ + 3];

    if (t0 == 0) {               // block-uniform branch, no divergence
        a[0] = a[1] = a[2] = make_float4(0.f, 0.f, 0.f, 0.f);
    } else {
        a[0] = xr[-3 * C4_];
        a[1] = xr[-2 * C4_];
        a[2] = xr[-1 * C4_];
    }

    #pragma unroll
    for (int i = 0; i < TT_; ++i)
        a[3 + i] = xr[i * C4_];

    const float4 k0 = kern[0 * C4_ + c4];
    const float4 k1 = kern[1 * C4_ + c4];
    const float4 k2 = kern[2 * C4_ + c4];
    const float4 k3 = kern[3 * C4_ + c4];

    // Fence: nothing crosses. Loads above cannot sink into the compute cluster;
    // compute below cannot hoist. First use of a[3] then waits at vmcnt(N>0),
    // with the remaining loads still in flight.
    __builtin_amdgcn_sched_barrier(0);

    #pragma unroll
    for (int i = 0; i < TT_; ++i) {
        const float4 cur = a[3 + i];
        const float4 w1  = a[2 + i];
        const float4 w2  = a[1 + i];
        const float4 w3  = a[0 + i];
        float4 r;
        r.x = fmaf(k0.x, cur.x, fmaf(k1.x, w1.x, fmaf(k2.x, w2.x, k3.x * w3.x)));
        r.y = fmaf(k0.y, cur.y, fmaf(k1.y, w1.y, fmaf(k2.y, w2.y, k3.y * w3.y)));
        r.z = fmaf(k0.z, cur.z, fmaf(k1.z, w1.z, fmaf(k2.z, w2.z, k3.z * w3.z)));
        r.w = fmaf(k0.w, cur.w, fmaf(k1.w, w1.w, fmaf(k2.w, w2.w, k3.w * w3.w)));
        r.x = silu_f(r.x); r.y = silu_f(r.y); r.z = silu_f(r.z); r.w = silu_f(r.w);
        yr[i * C4_] = r;   // plain store, drains through L2
    }

    // Fused next_cache = x[:, T-3:, :] from the already-loaded tail rows.
    if (t0 == T_ - TT_) {
        float4* cb = cache + (size_t)b * (K_ - 1) * C4_ + c4;
        cb[0 * C4_] = a[TT_ + 0];   // x[T-3]
        cb[1 * C4_] = a[TT_ + 1];   // x[T-2]
        cb[2 * C4_] = a[TT_ + 2];   // x[T-1]
    }
}

extern "C" void kernel_launch(void* const* d_in, const int* in_sizes, int n_in,
                              void* d_out, int out_size, void* d_ws, size_t ws_size,
                              hipStream_t stream)
{
    const float4* x    = (const float4*)d_in[0];
    const float4* kern = (const float4*)d_in[1];
    float*        out  = (float*)d_out;

    float4* y     = (float4*)out;
    float4* cache = (float4*)(out + (size_t)B_ * T_ * C_);

    dim3 grid(T_ / TT_, B_);   // (256, 4) = 1024 blocks
    dim3 block(C4_);           // 512 threads
    dwconv_silu_kernel<<<grid, block, 0, stream>>>(x, kern, y, cache);
}

// Round 3
// 227.673 us; speedup vs baseline: 1.0399x; 1.0399x over previous
//
#include <hip/hip_runtime.h>
#include <math.h>

// Causal depthwise conv1d K=4 + SiLU. x (B=4, T=4096, C=2048) fp32, kernel (4, C) fp32.
// y[b,t,c] = silu( sum_j k[j,c] * x[b,t-j,c] ), zero-padded; next_cache = x[:, T-3:, :].
//
// R4 post-mortem: sched_barrier fence was defeated (VGPR 56, needed >=92 if the 23-load
//   cluster had survived) AND kern loads were issued last but consumed first -> full
//   vmcnt(0) drain before compute. Effective MLP ~4 KB/CU (Little's law at 2.65 TB/s),
//   Occupancy 31%. Three per-thread schedules all pinned at 81-83us: the constraint is
//   per-CU memory-level parallelism, not the instruction schedule.
// R5: adopt the shape that measurably streams 6+ TB/s on this chip (fillBuffer 6.6 TB/s,
//   m13 copy 6.29 TB/s): 256-thread blocks, 8192-block grid (32 blocks/CU queued,
//   continuous backfill), tiny straight-line body: TT=4 rows/thread, 11 independent
//   loads (kern first: L1-hot, keeps x-load waits graduated), 4 stores. Wave-level
//   parallelism supplies MLP even if the scheduler serializes per-thread loads.

#define B_   4
#define T_   4096
#define C_   2048
#define K_   4
#define C4_  (C_ / 4)   // 512 float4 groups per row
#define TG_  4          // t rows per thread
#define NT_  (T_ / TG_) // 1024 t-groups

__device__ __forceinline__ float silu_f(float v) {
    // v * 1/(1+e^-v); raw v_rcp_f32 (approx, ~1ulp).
    return v * __builtin_amdgcn_rcpf(1.f + __expf(-v));
}

__global__ __launch_bounds__(256, 4) void dwconv_silu_kernel(
    const float4* __restrict__ x,      // [B, T, C4]
    const float4* __restrict__ kern,   // [K, C4]
    float4* __restrict__ y,            // [B, T, C4]
    float4* __restrict__ cache)        // [B, K-1, C4]
{
    // Linear thread id over (b, t-group, c4): wave lanes span 64 consecutive c4
    // -> every load/store is a contiguous 1 KB wave transaction.
    const int j  = blockIdx.x * 256 + threadIdx.x;
    const int c4 = j & (C4_ - 1);
    const int tg = (j >> 9) & (NT_ - 1);
    const int b  = j >> 19;            // 9 bits c4 + 10 bits tg
    const int t0 = tg * TG_;

    const float4* xp = x + (((size_t)b * T_ + t0) * C4_ + c4);

    // kern loads first: 32 KB total, L1/L2-resident after the first blocks, return
    // fast -> later x-load waits are graduated vmcnt(N), never a full drain.
    const float4 k0 = kern[0 * C4_ + c4];
    const float4 k1 = kern[1 * C4_ + c4];
    const float4 k2 = kern[2 * C4_ + c4];
    const float4 k3 = kern[3 * C4_ + c4];

    // Halo rows x[t0-3..t0-1]; tg is block-uniform so this branch never diverges.
    float4 m3, m2, m1;
    if (t0 == 0) {
        m3 = m2 = m1 = make_float4(0.f, 0.f, 0.f, 0.f);
    } else {
        m3 = xp[-3 * C4_];
        m2 = xp[-2 * C4_];
        m1 = xp[-1 * C4_];
    }
    // Body rows x[t0..t0+3] — 4 more independent loads.
    const float4 a0 = xp[0 * C4_];
    const float4 a1 = xp[1 * C4_];
    const float4 a2 = xp[2 * C4_];
    const float4 a3 = xp[3 * C4_];

    // Keep the load cluster above the compute cluster.
    __builtin_amdgcn_sched_barrier(0);

#define CONV1(r, a, w1, w2, w3)                                              \
    r.x = fmaf(k0.x, a.x, fmaf(k1.x, w1.x, fmaf(k2.x, w2.x, k3.x * w3.x)));  \
    r.y = fmaf(k0.y, a.y, fmaf(k1.y, w1.y, fmaf(k2.y, w2.y, k3.y * w3.y)));  \
    r.z = fmaf(k0.z, a.z, fmaf(k1.z, w1.z, fmaf(k2.z, w2.z, k3.z * w3.z)));  \
    r.w = fmaf(k0.w, a.w, fmaf(k1.w, w1.w, fmaf(k2.w, w2.w, k3.w * w3.w)));  \
    r.x = silu_f(r.x); r.y = silu_f(r.y); r.z = silu_f(r.z); r.w = silu_f(r.w);

    float4 r0, r1, r2, r3;
    CONV1(r0, a0, m1, m2, m3)
    CONV1(r1, a1, a0, m1, m2)
    CONV1(r2, a2, a1, a0, m1)
    CONV1(r3, a3, a2, a1, a0)
#undef CONV1

    float4* yp = y + (((size_t)b * T_ + t0) * C4_ + c4);
    yp[0 * C4_] = r0;
    yp[1 * C4_] = r1;
    yp[2 * C4_] = r2;
    yp[3 * C4_] = r3;

    // Fused next_cache = x[:, T-3:, :]: the last t-group (t0 = T-4) already holds
    // a1 = x[T-3], a2 = x[T-2], a3 = x[T-1].
    if (tg == NT_ - 1) {
        float4* cb = cache + (size_t)b * (K_ - 1) * C4_ + c4;
        cb[0 * C4_] = a1;
        cb[1 * C4_] = a2;
        cb[2 * C4_] = a3;
    }
}

extern "C" void kernel_launch(void* const* d_in, const int* in_sizes, int n_in,
                              void* d_out, int out_size, void* d_ws, size_t ws_size,
                              hipStream_t stream)
{
    const float4* x    = (const float4*)d_in[0];
    const float4* kern = (const float4*)d_in[1];
    float*        out  = (float*)d_out;

    float4* y     = (float4*)out;
    float4* cache = (float4*)(out + (size_t)B_ * T_ * C_);

    const int total_threads = B_ * NT_ * C4_;          // 2,097,152
    dim3 grid(total_threads / 256);                    // 8192 blocks
    dim3 block(256);
    dwconv_silu_kernel<<<grid, block, 0, stream>>>(x, kern, y, cache);
}